// Round 8
// baseline (380.809 us; speedup 1.0000x reference)
//
#include <hip/hip_runtime.h>
#include <math.h>

#define BLK 256
#define NB1 1024                    // round-0 coarse bins (v*128)
#define NB2 2048                    // round-1 sub-bins (aliases hsel)
#define CSH 42
#define QMASK ((1ULL << CSH) - 1ULL)

__device__ __forceinline__ float bce_logits(float x, float t){
    return fmaxf(x, 0.f) - x * t + log1pf(expf(-fabsf(x)));
}
__device__ __forceinline__ float smooth_l1(float x){
    float ax = fabsf(x);
    return ax < 1.f ? 0.5f * x * x : ax - 0.5f;
}

// One kernel. Grid (63,B): per-block map work (4 anchors/thread, GT y-cull),
// then per-slice ticket; the LAST block of each (scale,image) slice runs that
// slice's hard-negative top-K-sum select in-place (2-round packed histogram),
// overlapping other slices' map work. Final global ticket -> output.
__global__ __launch_bounds__(BLK)
void det_all(const float* __restrict__ pred0,
             const float* __restrict__ pred1,
             const float* __restrict__ pred2,
             const float* __restrict__ gtb,   // (B,32,4)
             const int*   __restrict__ gtl,   // (B,32)
             float* __restrict__ vals,        // (B,64512) neg BCE or -1
             float* __restrict__ loss_slot,   // 63*B
             int*   __restrict__ pcnt_slot,   // 63*B
             unsigned* __restrict__ slice_tk, // 192 (zeroed)
             double* __restrict__ slice_tot,  // 192
             unsigned* __restrict__ done_tk,  // 1 (zeroed)
             float* __restrict__ out, int B)
{
    const int b  = blockIdx.y;
    const int bx = blockIdx.x;

    const float* pred; int s, qloc, P, logW, nb; float stride_f; size_t vbase;
    if (bx < 48){      s=0; pred=pred0; P=16384; logW=7; nb=48; stride_f= 8.f; qloc= bx      << 8; vbase=(size_t)b*49152; }
    else if (bx < 60){ s=1; pred=pred1; P= 4096; logW=6; nb=12; stride_f=16.f; qloc=(bx-48) << 8; vbase=(size_t)B*49152 + (size_t)b*12288; }
    else {             s=2; pred=pred2; P= 1024; logW=5; nb= 3; stride_f=32.f; qloc=(bx-60) << 8; vbase=(size_t)B*49152 + (size_t)B*12288 + (size_t)b*3072; }

    const int sb  = s * B + b;
    const int tid = threadIdx.x;
    const int lane = tid & 63, w = tid >> 6;

    // ---------------- map phase ----------------
    const int lq  = 2*logW - 2;
    const int Q4  = 1 << lq;
    const int a   = qloc >> lq;            // block-uniform
    const int pix0 = (qloc - a*Q4 + tid) << 2;

    const float half = 0.5f * (float)(3 + a) * stride_f;

    const int pixLo = (qloc - a*Q4) << 2;
    const int y0 = pixLo >> logW, y1 = (pixLo + BLK*4 - 1) >> logW;
    const float ymin = ((float)y0 + 0.5f) * stride_f - half;
    const float ymax = ((float)y1 + 0.5f) * stride_f + half;

    __shared__ float4 sg[32];
    __shared__ float  sarea[32];
    __shared__ int    sl[32];
    __shared__ int    s_cnt;
    __shared__ unsigned long long hsel[2][NB1];   // 16 KB; aliased in round 1
    __shared__ unsigned long long waveT[4];
    __shared__ unsigned long long waveOff[5];
    __shared__ unsigned long long sh_aboveQ;
    __shared__ double sh_sel;
    __shared__ float  sh_ml;
    __shared__ float  wsum[4];
    __shared__ int    wcnt[4];
    __shared__ int    sh_b1, sh_rem, sh_done, sh_K, sh_win, sh_last;

    {
        bool keep = false; float4 G;
        if (tid < 32){
            G = ((const float4*)gtb)[b * 32 + tid];
            keep = (G.y < ymax) && (G.w > ymin);
        }
        unsigned long long m = __ballot(keep);
        if (tid < 64){
            if (keep){
                int idx = (int)__popcll(m & ((1ULL << tid) - 1ULL));
                sg[idx] = G;
                sarea[idx] = (G.z - G.x) * (G.w - G.y);
                sl[idx] = gtl[b * 32 + tid];
            }
            if (tid == 0) s_cnt = (int)__popcll(m);
        }
    }
    __syncthreads();
    const int cnt = s_cnt;

    const int x0 = pix0 & ((1 << logW) - 1);
    const int y  = pix0 >> logW;
    const float cy = ((float)y + 0.5f) * stride_f;
    const float Ay = cy - half, Ay2 = cy + half;
    const float area_a = (2.f * half) * (2.f * half);

    float ax[4], az[4];
    #pragma unroll
    for (int j = 0; j < 4; ++j){
        float cx = ((float)(x0 + j) + 0.5f) * stride_f;
        ax[j] = cx - half; az[j] = cx + half;
    }

    float bi[4] = {-1.f, -1.f, -1.f, -1.f};
    float bd[4] = { 1.f,  1.f,  1.f,  1.f};
    int   bg[4] = {0, 0, 0, 0};

    for (int g = 0; g < cnt; ++g){
        const float4 G = sg[g];
        const float sab = area_a + sarea[g];
        const float h = fmaxf(fminf(Ay2, G.w) - fmaxf(Ay, G.y), 0.f);
        #pragma unroll
        for (int j = 0; j < 4; ++j){
            float wdt = fmaxf(fminf(az[j], G.z) - fmaxf(ax[j], G.x), 0.f);
            float inter = wdt * h;
            float d = (sab - inter) + 1e-9f;
            if (inter * bd[j] > bi[j] * d){ bi[j] = inter; bd[j] = d; bg[j] = g; }
        }
    }

    const size_t cP = (size_t)P;
    const float* pp = pred + ((size_t)b * 24 + (size_t)a * 8) * cP + (size_t)pix0;
    const float4 p4v = *(const float4*)(pp + 4 * cP);
    const float p4a[4] = {p4v.x, p4v.y, p4v.z, p4v.w};

    float vout[4];
    float loss = 0.f; int pc = 0;
    #pragma unroll
    for (int j = 0; j < 4; ++j){
        const bool pos = 2.f * bi[j] >= bd[j];    // iou >= 0.5
        const bool neg = bi[j] < 0.4f * bd[j];    // iou <  0.4
        vout[j] = neg ? bce_logits(p4a[j], 0.f) : -1.f;
        if (pos){
            pc++;
            const float4 G = sg[bg[j]];
            float axc = (ax[j] + az[j]) * 0.5f, ayc = (Ay + Ay2) * 0.5f;
            float aw = fmaxf(az[j] - ax[j], 1e-6f), ah = fmaxf(Ay2 - Ay, 1e-6f);
            float gxc = (G.x + G.z) * 0.5f, gyc = (G.y + G.w) * 0.5f;
            float gw = fmaxf(G.z - G.x, 1e-6f), gh = fmaxf(G.w - G.y, 1e-6f);
            float p0 = pp[0 * cP + j];
            float p1 = pp[1 * cP + j];
            float p2 = pp[2 * cP + j];
            float p3 = pp[3 * cP + j];
            loss += smooth_l1(p0 - (gxc - axc) / aw);
            loss += smooth_l1(p1 - (gyc - ayc) / ah);
            loss += smooth_l1(p2 - logf(gw / aw));
            loss += smooth_l1(p3 - logf(gh / ah));
            loss += bce_logits(p4a[j], 1.f);
            float c0 = pp[5 * cP + j];
            float c1 = pp[6 * cP + j];
            float c2 = pp[7 * cP + j];
            float m = fmaxf(c0, fmaxf(c1, c2));
            float lse = m + logf(expf(c0 - m) + expf(c1 - m) + expf(c2 - m));
            int tg = sl[bg[j]];
            float ct = (tg == 0) ? c0 : ((tg == 1) ? c1 : c2);
            loss += lse - ct;
        }
    }
    float4 vo = {vout[0], vout[1], vout[2], vout[3]};
    *(float4*)(vals + vbase + (size_t)(qloc - a*Q4 + tid + a*Q4) * 4) = vo;

    for (int off = 32; off > 0; off >>= 1){
        loss += __shfl_down(loss, off);
        pc   += __shfl_down(pc, off);
    }
    if (lane == 0){ wsum[w] = loss; wcnt[w] = pc; }
    __syncthreads();                 // also drains vals stores (vmcnt) per wave
    if (tid == 0){
        float S = 0.f; int C = 0;
        for (int i = 0; i < 4; ++i){ S += wsum[i]; C += wcnt[i]; }
        loss_slot[b * 63 + bx] = S;
        pcnt_slot[b * 63 + bx] = C;
        __threadfence();             // release vals + slots to device scope
        unsigned old = atomicAdd(&slice_tk[sb], 1u);
        sh_win = (old == (unsigned)(nb - 1));
        if (sh_win) __threadfence(); // acquire other blocks' stores
    }
    __syncthreads();
    if (!sh_win) return;

    // ---------------- select phase (last block of slice) ----------------
    const int N = (s == 0) ? 49152 : (s == 1) ? 12288 : 3072;
    size_t base = 0;
    if (s >= 1) base += (size_t)B * 49152;
    if (s >= 2) base += (size_t)B * 12288;
    const float* V = vals + base + (size_t)b * (size_t)N;

    // slice map-loss / pos-count from slots (wave 0)
    {
        const int off0 = b * 63 + ((s == 0) ? 0 : (s == 1) ? 48 : 60);
        float ml = 0.f; int C = 0;
        if (tid < nb){ ml = loss_slot[off0 + tid]; C = pcnt_slot[off0 + tid]; }
        if (tid < 64){
            for (int off = 32; off > 0; off >>= 1){
                ml += __shfl_down(ml, off);
                C  += __shfl_down(C, off);
            }
            if (tid == 0){ sh_ml = ml; sh_K = 3 * max(1, C); sh_done = 0; }
        }
    }
    for (int i = tid; i < NB1; i += BLK){ hsel[0][i] = 0ULL; hsel[1][i] = 0ULL; }
    __syncthreads();

    // ---- round 0: coarse 1024-bin histogram (v*128), 2 replicas ----
    const int rep = w & 1;
    for (int i = tid * 4; i < N; i += BLK * 4){
        float4 v4 = *(const float4*)(V + i);
        #pragma unroll
        for (int j = 0; j < 4; ++j){
            float v = (j == 0) ? v4.x : (j == 1) ? v4.y : (j == 2) ? v4.z : v4.w;
            if (!(v >= 0.f)) continue;
            int bin = min((int)(v * 128.f), NB1 - 1);
            unsigned long long p = (1ULL << CSH) |
                (unsigned long long)(unsigned)(int)(v * 4194304.f);   // v*2^22
            atomicAdd(&hsel[rep][bin], p);
        }
    }
    __syncthreads();

    {   // descending prefix, 4 bins/thread
        const int start = NB1 - 4 * (tid + 1);
        unsigned long long chunk[4]; unsigned long long tot = 0ULL;
        #pragma unroll
        for (int i = 0; i < 4; ++i){ chunk[i] = hsel[0][start+i] + hsel[1][start+i]; tot += chunk[i]; }
        unsigned long long ci = tot;
        #pragma unroll
        for (int off = 1; off < 64; off <<= 1){
            unsigned long long cu = __shfl_up(ci, off);
            if (lane >= off) ci += cu;
        }
        if (lane == 63) waveT[w] = ci;
        __syncthreads();
        if (tid == 0){
            unsigned long long acc = 0ULL;
            #pragma unroll
            for (int i = 0; i < 4; ++i){ waveOff[i] = acc; acc += waveT[i]; }
            waveOff[4] = acc;
            if (sh_K >= (int)(acc >> CSH)){      // keep all negatives
                sh_done = 1;
                sh_sel = (double)(acc & QMASK) * (1.0 / 4194304.0);
            }
        }
        __syncthreads();
        if (!sh_done){
            const int K = sh_K;
            const unsigned long long giP = waveOff[w] + ci;
            const unsigned long long geP = giP - tot;
            const int gi = (int)(giP >> CSH);
            const int ge = (int)(geP >> CSH);
            if (ge < K && K <= gi){
                int aboveC = ge;
                unsigned long long aboveQ = geP & QMASK;
                #pragma unroll
                for (int i = 3; i >= 0; --i){
                    int c = (int)(chunk[i] >> CSH);
                    if (aboveC + c >= K){
                        sh_b1 = start + i; sh_rem = K - aboveC; sh_aboveQ = aboveQ;
                        break;
                    }
                    aboveC += c;
                    aboveQ += chunk[i] & QMASK;
                }
            }
            __syncthreads();
        }
    }

    // ---- round 1: 2048 sub-bins within boundary bin (width 2^-18) ----
    if (!sh_done){
        unsigned long long* Hs = (unsigned long long*)hsel;   // 2048 bins
        for (int i = tid; i < NB2; i += BLK) Hs[i] = 0ULL;
        __syncthreads();
        const int b1 = sh_b1;
        for (int i = tid * 4; i < N; i += BLK * 4){
            float4 v4 = *(const float4*)(V + i);
            #pragma unroll
            for (int j = 0; j < 4; ++j){
                float v = (j == 0) ? v4.x : (j == 1) ? v4.y : (j == 2) ? v4.z : v4.w;
                if (!(v >= 0.f)) continue;
                float t = v * 128.f;                    // exact
                int bin = min((int)t, NB1 - 1);
                if (bin != b1) continue;
                float frac = t - (float)bin;            // exact
                int sub = min((int)(frac * 2048.f), NB2 - 1);
                unsigned long long p = (1ULL << CSH) |
                    (unsigned long long)(unsigned)(int)(v * 4194304.f);
                atomicAdd(&Hs[sub], p);
            }
        }
        __syncthreads();

        const int start = NB2 - 8 * (tid + 1);
        unsigned long long chunk[8]; unsigned long long tot = 0ULL;
        #pragma unroll
        for (int i = 0; i < 8; ++i){ chunk[i] = Hs[start + i]; tot += chunk[i]; }
        unsigned long long ci = tot;
        #pragma unroll
        for (int off = 1; off < 64; off <<= 1){
            unsigned long long cu = __shfl_up(ci, off);
            if (lane >= off) ci += cu;
        }
        if (lane == 63) waveT[w] = ci;
        __syncthreads();
        if (tid == 0){
            unsigned long long acc = 0ULL;
            #pragma unroll
            for (int i = 0; i < 4; ++i){ waveOff[i] = acc; acc += waveT[i]; }
            waveOff[4] = acc;
        }
        __syncthreads();
        const int rem = sh_rem;
        const unsigned long long giP = waveOff[w] + ci;
        const unsigned long long geP = giP - tot;
        const int gi = (int)(giP >> CSH);
        const int ge = (int)(geP >> CSH);
        if (ge < rem && rem <= gi){
            int aboveC = ge;
            unsigned long long aboveQ = geP & QMASK;
            int sub = start;
            #pragma unroll
            for (int i = 7; i >= 0; --i){
                int c = (int)(chunk[i] >> CSH);
                if (aboveC + c >= rem){ sub = start + i; break; }
                aboveC += c;
                aboveQ += chunk[i] & QMASK;
            }
            float thresh = (float)b1 * (1.f / 128.f) + (float)sub * (1.f / 262144.f);
            sh_sel = (double)(sh_aboveQ + aboveQ) * (1.0 / 4194304.0)
                   + (double)(rem - aboveC) * (double)thresh;
        }
        __syncthreads();
    }

    // ---- slice total + global ticket; last slice reduces all ----
    if (tid == 0){
        slice_tot[sb] = (double)sh_ml + sh_sel;
        __threadfence();
        unsigned t = atomicAdd(done_tk, 1u);
        sh_last = (t == (unsigned)(3 * B - 1));
        if (sh_last) __threadfence();
    }
    __syncthreads();
    if (sh_last){
        double p = (tid < 3 * B) ? slice_tot[tid] : 0.0;
        for (int off = 32; off > 0; off >>= 1) p += __shfl_down(p, off);
        __shared__ double wred[4];
        if (lane == 0) wred[w] = p;
        __syncthreads();
        if (tid == 0){
            double tot = 0.0;
            for (int i = 0; i < 4; ++i) tot += wred[i];
            out[0] = (float)(tot / (double)B);
        }
    }
}

extern "C" void kernel_launch(void* const* d_in, const int* in_sizes, int n_in,
                              void* d_out, int out_size, void* d_ws, size_t ws_size,
                              hipStream_t stream)
{
    const float* gtb = (const float*)d_in[6];
    const int*   gtl = (const int*)d_in[7];
    const int B = in_sizes[6] / (32 * 4);   // 64

    unsigned* done      = (unsigned*)d_ws;                         // @0
    unsigned* slice_tk  = (unsigned*)((char*)d_ws + 64);           // 192 u32
    double*   slice_tot = (double*)((char*)d_ws + 1024);           // 192 f64
    float*    loss_slot = (float*)((char*)d_ws + 4096);            // 63*B f32
    int*      pcnt_slot = (int*)((char*)d_ws + 4096 + 16384);      // 63*B i32
    float*    vals      = (float*)((char*)d_ws + 40960);           // B*64512 f32

    hipMemsetAsync(d_ws, 0, 1024, stream);   // tickets only

    det_all<<<dim3(63, B), BLK, 0, stream>>>(
        (const float*)d_in[0], (const float*)d_in[2], (const float*)d_in[4],
        gtb, gtl, vals, loss_slot, pcnt_slot, slice_tk, slice_tot, done,
        (float*)d_out, B);
}

// Round 9
// 204.046 us; speedup vs baseline: 1.8663x; 1.8663x over previous
//
#include <hip/hip_runtime.h>
#include <math.h>

#define BLK 256
#define SBLK 1024
#define NBINS 2048
#define SREP 8
#define SPAD 2049                   // pad so replicas start on distinct banks
#define CSH 42
#define QMASK ((1ULL << CSH) - 1ULL)

__device__ __forceinline__ float bce_logits(float x, float t){
    return fmaxf(x, 0.f) - x * t + log1pf(expf(-fabsf(x)));
}
__device__ __forceinline__ float smooth_l1(float x){
    float ax = fabsf(x);
    return ax < 1.f ? 0.5f * x * x : ax - 0.5f;
}

// All 3 scales, one dispatch, 4 anchors/thread, block GT y-cull (culled GTs
// have IoU==0 exactly -> first-argmax/pos/neg semantics preserved).
// Per-block results go to plain-store slots (no zero-init, no atomics).
__global__ __launch_bounds__(BLK)
void det_map_all(const float* __restrict__ pred0,
                 const float* __restrict__ pred1,
                 const float* __restrict__ pred2,
                 const float* __restrict__ gtb,   // (B,32,4)
                 const int*   __restrict__ gtl,   // (B,32)
                 float* __restrict__ vals,        // (B,64512) neg BCE or -1
                 float* __restrict__ loss_slot,   // 63*B per-block map loss
                 int*   __restrict__ pcnt_slot,   // 63*B per-block pos count
                 unsigned* __restrict__ done_cnt, // zeroed by block (0,0)
                 int B)
{
    const int b  = blockIdx.y;
    const int bx = blockIdx.x;

    const float* pred; int s, qloc, P, logW; float stride_f; size_t vbase;
    if (bx < 48){      s=0; pred=pred0; P=16384; logW=7; stride_f= 8.f; qloc= bx      << 8; vbase=(size_t)b*49152; }
    else if (bx < 60){ s=1; pred=pred1; P= 4096; logW=6; stride_f=16.f; qloc=(bx-48) << 8; vbase=(size_t)B*49152 + (size_t)b*12288; }
    else {             s=2; pred=pred2; P= 1024; logW=5; stride_f=32.f; qloc=(bx-60) << 8; vbase=(size_t)B*49152 + (size_t)B*12288 + (size_t)b*3072; }

    const int tid = threadIdx.x;
    const int lq  = 2*logW - 2;            // log2(P/4)
    const int Q4  = 1 << lq;
    const int a   = qloc >> lq;            // block-uniform (Q4 % 256 == 0)
    const int pix0 = (qloc - a*Q4 + tid) << 2;

    const float half = 0.5f * (float)(3 + a) * stride_f;

    // block anchor y-extent for culling
    const int pixLo = (qloc - a*Q4) << 2;
    const int y0 = pixLo >> logW, y1 = (pixLo + BLK*4 - 1) >> logW;
    const float ymin = ((float)y0 + 0.5f) * stride_f - half;
    const float ymax = ((float)y1 + 0.5f) * stride_f + half;

    __shared__ float4 sg[32];
    __shared__ float  sarea[32];
    __shared__ int    sl[32];
    __shared__ int    s_cnt;

    {
        bool keep = false; float4 G;
        if (tid < 32){
            G = ((const float4*)gtb)[b * 32 + tid];
            keep = (G.y < ymax) && (G.w > ymin);
        }
        unsigned long long m = __ballot(keep);
        if (tid < 64){
            if (keep){
                int idx = (int)__popcll(m & ((1ULL << tid) - 1ULL));
                sg[idx] = G;
                sarea[idx] = (G.z - G.x) * (G.w - G.y);
                sl[idx] = gtl[b * 32 + tid];
            }
            if (tid == 0) s_cnt = (int)__popcll(m);
        }
    }
    __syncthreads();
    const int cnt = s_cnt;

    const int x0 = pix0 & ((1 << logW) - 1);
    const int y  = pix0 >> logW;
    const float cy = ((float)y + 0.5f) * stride_f;
    const float Ay = cy - half, Ay2 = cy + half;
    const float area_a = (2.f * half) * (2.f * half);

    float ax[4], az[4];
    #pragma unroll
    for (int j = 0; j < 4; ++j){
        float cx = ((float)(x0 + j) + 0.5f) * stride_f;
        ax[j] = cx - half; az[j] = cx + half;
    }

    float bi[4] = {-1.f, -1.f, -1.f, -1.f};
    float bd[4] = { 1.f,  1.f,  1.f,  1.f};
    int   bg[4] = {0, 0, 0, 0};

    for (int g = 0; g < cnt; ++g){
        const float4 G = sg[g];
        const float sab = area_a + sarea[g];
        const float h = fmaxf(fminf(Ay2, G.w) - fmaxf(Ay, G.y), 0.f);
        #pragma unroll
        for (int j = 0; j < 4; ++j){
            float wdt = fmaxf(fminf(az[j], G.z) - fmaxf(ax[j], G.x), 0.f);
            float inter = wdt * h;
            float d = (sab - inter) + 1e-9f;
            if (inter * bd[j] > bi[j] * d){ bi[j] = inter; bd[j] = d; bg[j] = g; }
        }
    }

    const size_t cP = (size_t)P;
    const float* pp = pred + ((size_t)b * 24 + (size_t)a * 8) * cP + (size_t)pix0;
    const float4 p4v = *(const float4*)(pp + 4 * cP);
    const float p4a[4] = {p4v.x, p4v.y, p4v.z, p4v.w};

    float vout[4];
    float loss = 0.f; int pc = 0;
    #pragma unroll
    for (int j = 0; j < 4; ++j){
        const bool pos = 2.f * bi[j] >= bd[j];    // iou >= 0.5
        const bool neg = bi[j] < 0.4f * bd[j];    // iou <  0.4
        vout[j] = neg ? bce_logits(p4a[j], 0.f) : -1.f;
        if (pos){
            pc++;
            const float4 G = sg[bg[j]];
            float axc = (ax[j] + az[j]) * 0.5f, ayc = (Ay + Ay2) * 0.5f;
            float aw = fmaxf(az[j] - ax[j], 1e-6f), ah = fmaxf(Ay2 - Ay, 1e-6f);
            float gxc = (G.x + G.z) * 0.5f, gyc = (G.y + G.w) * 0.5f;
            float gw = fmaxf(G.z - G.x, 1e-6f), gh = fmaxf(G.w - G.y, 1e-6f);
            float p0 = pp[0 * cP + j];
            float p1 = pp[1 * cP + j];
            float p2 = pp[2 * cP + j];
            float p3 = pp[3 * cP + j];
            loss += smooth_l1(p0 - (gxc - axc) / aw);
            loss += smooth_l1(p1 - (gyc - ayc) / ah);
            loss += smooth_l1(p2 - logf(gw / aw));
            loss += smooth_l1(p3 - logf(gh / ah));
            loss += bce_logits(p4a[j], 1.f);
            float c0 = pp[5 * cP + j];
            float c1 = pp[6 * cP + j];
            float c2 = pp[7 * cP + j];
            float m = fmaxf(c0, fmaxf(c1, c2));
            float lse = m + logf(expf(c0 - m) + expf(c1 - m) + expf(c2 - m));
            int tg = sl[bg[j]];
            float ct = (tg == 0) ? c0 : ((tg == 1) ? c1 : c2);
            loss += lse - ct;
        }
    }
    float4 vo = {vout[0], vout[1], vout[2], vout[3]};
    *(float4*)(vals + vbase + (size_t)(qloc - a*Q4 + tid) * 4 + (size_t)a * P) = vo;

    for (int off = 32; off > 0; off >>= 1){
        loss += __shfl_down(loss, off);
        pc   += __shfl_down(pc, off);
    }
    __shared__ float wsum[BLK / 64];
    __shared__ int   wcnt[BLK / 64];
    if ((tid & 63) == 0){ wsum[tid >> 6] = loss; wcnt[tid >> 6] = pc; }
    __syncthreads();
    if (tid == 0){
        float S = 0.f; int C = 0;
        for (int i = 0; i < BLK / 64; ++i){ S += wsum[i]; C += wcnt[i]; }
        loss_slot[b * 63 + bx] = S;
        pcnt_slot[b * 63 + bx] = C;
        if (b == 0 && bx == 0) *done_cnt = 0u;   // visible to select via stream order
    }
}

// One 1024-thread block per (scale,image). SINGLE scan: 2048 bins at v*512
// (width 2^-9), 8 lane-rotated padded replicas of the packed
// (count<<42 | v*2^22) histogram, closed-form top-K sum:
//   sum = aboveQ*2^-22 + rem * binLowerBound   (error <= rem*2^-9, << tol).
// Then slice slot + ticket; last block reduces all slices -> out.
__global__ __launch_bounds__(SBLK)
void det_select(const float* __restrict__ vals,
                const float* __restrict__ loss_slot,
                const int* __restrict__ pcnt_slot,
                double* __restrict__ slice_tot,   // 3*B
                unsigned* __restrict__ done_cnt,
                float* __restrict__ out, int B)
{
    const int sb = blockIdx.x;
    const int s = sb / B, b = sb - s * B;
    const int N = (s == 0) ? 49152 : (s == 1) ? 12288 : 3072;
    size_t base = 0;
    if (s >= 1) base += (size_t)B * 49152;
    if (s >= 2) base += (size_t)B * 12288;
    const float* V = vals + base + (size_t)b * (size_t)N;

    const int tid = threadIdx.x;
    const int lane = tid & 63, w = tid >> 6;

    __shared__ unsigned long long h[SREP][SPAD];   // ~131 KB
    __shared__ unsigned long long waveT[16];
    __shared__ unsigned long long waveOff[17];
    __shared__ double sh_sel;
    __shared__ float sh_ml;
    __shared__ int sh_done, sh_K, sh_last;

    // ---- sum this slice's per-block map loss / pos count (wave 0) ----
    {
        const int nb   = (s == 0) ? 48 : (s == 1) ? 12 : 3;
        const int off0 = b * 63 + ((s == 0) ? 0 : (s == 1) ? 48 : 60);
        float ml = 0.f; int C = 0;
        if (tid < nb){ ml = loss_slot[off0 + tid]; C = pcnt_slot[off0 + tid]; }
        if (tid < 64){
            for (int off = 32; off > 0; off >>= 1){
                ml += __shfl_down(ml, off);
                C  += __shfl_down(C, off);
            }
            if (tid == 0){ sh_ml = ml; sh_K = 3 * max(1, C); sh_done = 0; }
        }
    }
    for (int i = tid; i < SREP * SPAD; i += SBLK)
        ((unsigned long long*)h)[i] = 0ULL;
    __syncthreads();

    // ---- single histogram scan ----
    const int rep = lane & (SREP - 1);
    for (int i = tid * 4; i < N; i += SBLK * 4){
        float4 v4 = *(const float4*)(V + i);
        #pragma unroll
        for (int j = 0; j < 4; ++j){
            float v = (j == 0) ? v4.x : (j == 1) ? v4.y : (j == 2) ? v4.z : v4.w;
            if (!(v >= 0.f)) continue;
            int bin = min((int)(v * 512.f), NBINS - 1);
            unsigned long long p = (1ULL << CSH) |
                (unsigned long long)(unsigned)(int)(v * 4194304.f);   // v*2^22
            atomicAdd(&h[rep][bin], p);
        }
    }
    __syncthreads();

    // ---- descending prefix over 2 bins/thread; closed-form top-K sum ----
    const int bhi = NBINS - 1 - 2 * tid;
    unsigned long long c0p = 0ULL, c1p = 0ULL;
    #pragma unroll
    for (int r = 0; r < SREP; ++r){ c0p += h[r][bhi]; c1p += h[r][bhi - 1]; }
    const unsigned long long pair = c0p + c1p;
    unsigned long long ci = pair;
    #pragma unroll
    for (int off = 1; off < 64; off <<= 1){
        unsigned long long cu = __shfl_up(ci, off);
        if (lane >= off) ci += cu;
    }
    if (lane == 63) waveT[w] = ci;
    __syncthreads();
    if (tid == 0){
        unsigned long long acc = 0ULL;
        #pragma unroll
        for (int i = 0; i < 16; ++i){ waveOff[i] = acc; acc += waveT[i]; }
        waveOff[16] = acc;
        if (sh_K >= (int)(acc >> CSH)){          // keep all negatives
            sh_done = 1;
            sh_sel = (double)(acc & QMASK) * (1.0 / 4194304.0);
        }
    }
    __syncthreads();

    if (!sh_done){
        const int K = sh_K;
        const unsigned long long giP = waveOff[w] + ci;
        const unsigned long long geP = giP - pair;
        const int gi = (int)(giP >> CSH);
        const int ge = (int)(geP >> CSH);
        if (ge < K && K <= gi){
            const int c0 = (int)(c0p >> CSH);
            int bin, aboveC; unsigned long long aboveQ;
            if (ge + c0 >= K){ bin = bhi;     aboveC = ge;      aboveQ = geP & QMASK; }
            else             { bin = bhi - 1; aboveC = ge + c0; aboveQ = (geP + c0p) & QMASK; }
            float thresh = (float)bin * (1.f / 512.f);
            sh_sel = (double)aboveQ * (1.0 / 4194304.0)
                   + (double)(K - aboveC) * (double)thresh;
        }
        __syncthreads();
    }

    // ---- slice total -> slot; last ticket block reduces all slices ----
    if (tid == 0){
        slice_tot[sb] = (double)sh_ml + sh_sel;
        __threadfence();
        unsigned t = atomicAdd(done_cnt, 1u);
        sh_last = (t == (unsigned)(gridDim.x - 1));
        if (sh_last) __threadfence();
    }
    __syncthreads();
    if (sh_last){
        double p = (tid < 3 * B) ? slice_tot[tid] : 0.0;
        for (int off = 32; off > 0; off >>= 1) p += __shfl_down(p, off);
        __shared__ double wred[16];
        if (lane == 0) wred[w] = p;
        __syncthreads();
        if (tid == 0){
            double tot = 0.0;
            for (int i = 0; i < 16; ++i) tot += wred[i];
            out[0] = (float)(tot / (double)B);
        }
    }
}

extern "C" void kernel_launch(void* const* d_in, const int* in_sizes, int n_in,
                              void* d_out, int out_size, void* d_ws, size_t ws_size,
                              hipStream_t stream)
{
    const float* gtb = (const float*)d_in[6];
    const int*   gtl = (const int*)d_in[7];
    const int B = in_sizes[6] / (32 * 4);   // 64

    unsigned* done      = (unsigned*)d_ws;                         // @0
    double*   slice_tot = (double*)((char*)d_ws + 64);             // 192 doubles
    float*    loss_slot = (float*)((char*)d_ws + 2048);            // 63*B floats
    int*      pcnt_slot = (int*)((char*)d_ws + 2048 + 16384);      // 63*B ints
    float*    vals      = (float*)((char*)d_ws + 36864);           // B*64512 floats

    det_map_all<<<dim3(63, B), BLK, 0, stream>>>(
        (const float*)d_in[0], (const float*)d_in[2], (const float*)d_in[4],
        gtb, gtl, vals, loss_slot, pcnt_slot, done, B);
    det_select<<<dim3(3 * B), SBLK, 0, stream>>>(
        vals, loss_slot, pcnt_slot, slice_tot, done, (float*)d_out, B);
}